// Round 18
// baseline (1680.578 us; speedup 1.0000x reference)
//
#include <hip/hip_runtime.h>

#define CH 1440
#define CW 1440
#define NC 32
#define EPSV 1e-3f
#define BSZ (9 * 2 * 64)   // uint4s per layer of Bfg

typedef __attribute__((ext_vector_type(8))) short bf16x8;
typedef __attribute__((ext_vector_type(16))) float f32x16;

union U16 { uint4 u; bf16x8 v; };

__device__ __forceinline__ unsigned pk2(float a, float b) {
    unsigned ua = __float_as_uint(a), ub = __float_as_uint(b);
    ua += 0x7fffu + ((ua >> 16) & 1u);
    ub += 0x7fffu + ((ub >> 16) & 1u);
    return (ua >> 16) | (ub & 0xffff0000u);
}
__device__ __forceinline__ float bfl(unsigned u) { return __uint_as_float(u << 16); }
__device__ __forceinline__ float bfh(unsigned u) { return __uint_as_float(u & 0xffff0000u); }

// ---------------- hand-rolled grid sync (no cg -> no spill trigger) ----------------
// __threadfence() = agent-scope fence (release+acquire) -> block barrier ->
// t0: count++ & spin -> barrier -> fence. Same semantics as cg sync.
__device__ __forceinline__ void gsync(int* cnt, int phase) {
    __threadfence();
    __syncthreads();
    if (threadIdx.x == 0) {
        __hip_atomic_fetch_add(&cnt[phase], 1, __ATOMIC_RELAXED, __HIP_MEMORY_SCOPE_AGENT);
        while (__hip_atomic_load(&cnt[phase], __ATOMIC_RELAXED, __HIP_MEMORY_SCOPE_AGENT)
               < (int)gridDim.x)
            __builtin_amdgcn_s_sleep(2);
    }
    __syncthreads();
    __threadfence();
}

__device__ __forceinline__ int vquery(const int* __restrict__ idx_map,
                                      const unsigned* __restrict__ pkey,
                                      unsigned cell, int n)
{
    int v = idx_map[cell];
    if (v < 0 || v >= n) return -1;
    return (pkey[v] == cell) ? v : -1;
}

// ---------------- per-tile conv body (r14 swapped-operand MFMA, verified) ----------
// rk loaded INSIDE (no state across syncs -> no spill, r15 lesson).
template<bool ADD_ID, bool F32OUT>
__device__ __forceinline__ void conv_tile(
    int tile,
    const unsigned short* __restrict__ in, const unsigned short* __restrict__ idn,
    void* __restrict__ outv, const uint4* __restrict__ Bf,
    const float* __restrict__ sh, const int* __restrict__ roff,
    int n, int l, int q, int h5)
{
    const int zoff = n * 64;
    const char* inB = (const char*)in;
    int p0 = tile << 5;
    int pr = p0 + q;
    bool rowok = pr < n;
    int prc = rowok ? pr : n - 1;

    int rk[9];
    #pragma unroll
    for (int k = 0; k < 9; ++k) rk[k] = roff[(size_t)k * n + prc];

    f32x16 acc = {0.f,0.f,0.f,0.f,0.f,0.f,0.f,0.f,0.f,0.f,0.f,0.f,0.f,0.f,0.f,0.f};

    #pragma unroll
    for (int g = 0; g < 3; ++g) {
        bool act[3];
        U16 a0[3], a1[3];
        #pragma unroll
        for (int j = 0; j < 3; ++j) {
            int k = g * 3 + j;
            act[j] = __any(rk[k] >= 0);
            if (act[j]) {
                int off = (rowok && rk[k] >= 0) ? rk[k] : zoff;
                const char* ap = inB + off + h5 * 16;
                a0[j].u = *(const uint4*)(ap);
                a1[j].u = *(const uint4*)(ap + 32);
            }
        }
        #pragma unroll
        for (int j = 0; j < 3; ++j) {
            int k = g * 3 + j;
            if (act[j]) {
                U16 b0, b1;
                b0.u = Bf[(k * 2 + 0) * 64 + l];
                b1.u = Bf[(k * 2 + 1) * 64 + l];
                acc = __builtin_amdgcn_mfma_f32_32x32x16_bf16(b0.v, a0[j].v, acc, 0, 0, 0);
                acc = __builtin_amdgcn_mfma_f32_32x32x16_bf16(b1.v, a1[j].v, acc, 0, 0, 0);
            }
        }
    }

    if (rowok) {
        #pragma unroll
        for (int g = 0; g < 4; ++g) {
            int ch = g * 8 + 4 * h5;
            float4 s4 = *(const float4*)(sh + ch);
            float y0 = acc[g * 4 + 0] + s4.x;
            float y1 = acc[g * 4 + 1] + s4.y;
            float y2 = acc[g * 4 + 2] + s4.z;
            float y3 = acc[g * 4 + 3] + s4.w;
            if (ADD_ID) {
                uint2 iv = *(const uint2*)(idn + (size_t)pr * 32 + ch);
                y0 += bfl(iv.x); y1 += bfh(iv.x);
                y2 += bfl(iv.y); y3 += bfh(iv.y);
            }
            y0 = fmaxf(y0, 0.f); y1 = fmaxf(y1, 0.f);
            y2 = fmaxf(y2, 0.f); y3 = fmaxf(y3, 0.f);
            if (F32OUT) {
                *(float4*)((float*)outv + (size_t)pr * 32 + ch) =
                    make_float4(y0, y1, y2, y3);
            } else {
                uint2 r;
                r.x = pk2(y0, y1); r.y = pk2(y2, y3);
                *(uint2*)((unsigned short*)outv + (size_t)pr * 32 + ch) = r;
            }
        }
    }
}

// ---------------- THE kernel: clear -> build -> prep -> 6 conv layers --------------
// One cooperative launch replaces 9 dispatches: kills 8 dispatch ramps + 8 implicit
// L2 writeback/invalidate boundaries; roff/Bfg/zero-row stay L2-warm across layers.
__global__ __launch_bounds__(256, 6) void k_all(
    const int* __restrict__ cb, const int* __restrict__ cy, const int* __restrict__ cx,
    const float* __restrict__ feats, const float* __restrict__ Wk,
    const float* __restrict__ bias, const float* __restrict__ gamma,
    const float* __restrict__ beta, const float* __restrict__ mean,
    const float* __restrict__ var,
    int* __restrict__ idx_map, unsigned* __restrict__ pkey, int* __restrict__ roff,
    uint4* __restrict__ Bfg, float* __restrict__ sh_all,
    unsigned short* __restrict__ xbf, unsigned short* __restrict__ tmpbf,
    unsigned short* __restrict__ hb, float* __restrict__ out,
    int* __restrict__ cnt, int n)
{
    int tid = threadIdx.x;
    int gstride = (int)gridDim.x * 256;
    int g0 = (int)blockIdx.x * 256 + tid;

    // ---- phase A: center-cell clear + pkey emit (r13 verified-query scheme) ----
    for (int i = g0; i < n; i += gstride) {
        unsigned key = ((unsigned)cb[i] * CH + (unsigned)cy[i]) * CW + (unsigned)cx[i];
        pkey[i] = key;
        idx_map[key] = -1;
    }
    gsync(cnt, 0);

    // ---- phase B: build map via atomicMax (numpy last-write-wins) ----
    for (int i = g0; i < n; i += gstride)
        atomicMax(&idx_map[pkey[i]], i);
    gsync(cnt, 1);

    // ---- phase C: rulebook + feats->bf16 + W-frags(BN-scaled) + zero rows ----
    for (int i = g0; i < n; i += gstride) {
        unsigned key = pkey[i];
        unsigned x = key % CW;
        unsigned y = (key / CW) % CH;
        roff[4 * n + i] = idx_map[key] * 64;   // own cell: cleared+built, trusted
        #pragma unroll
        for (int k = 0; k < 9; ++k) {
            if (k == 4) continue;
            int dy = k / 3 - 1, dx = k % 3 - 1;
            int ny = (int)y + dy, nx = (int)x + dx;
            int nb = -1;
            if (ny >= 0 && ny < CH && nx >= 0 && nx < CW)
                nb = vquery(idx_map, pkey, key + dy * CW + dx, n);
            roff[k * n + i] = (nb >= 0) ? nb * 64 : -1;
        }
    }
    for (int i = g0; i < n * NC / 8; i += gstride) {
        float4 a0 = *(const float4*)(feats + i * 8);
        float4 a1 = *(const float4*)(feats + i * 8 + 4);
        uint4 r;
        r.x = pk2(a0.x, a0.y); r.y = pk2(a0.z, a0.w);
        r.z = pk2(a1.x, a1.y); r.w = pk2(a1.z, a1.w);
        *(uint4*)(xbf + i * 8) = r;
    }
    if (g0 < 6 * 9 * 2 * 64) {
        int t = g0;
        int l_ = t & 63, h = (t >> 6) & 1;
        int rest = t >> 7;
        int k = rest % 9, layer = rest / 9;
        int o = l_ & 31;
        int lo = layer * 32 + o;
        float scv = gamma[lo] * rsqrtf(var[lo] + EPSV);
        if (k == 0 && h == 0 && l_ < 32)
            sh_all[lo] = (bias[lo] - mean[lo]) * scv + beta[lo];
        int c0 = h * 16 + 8 * (l_ >> 5);
        const float* wp = Wk + (size_t)layer * 9216 + k * 1024 + o;   // [c][o]
        uint4 r;
        r.x = pk2(wp[(c0 + 0) * 32] * scv, wp[(c0 + 1) * 32] * scv);
        r.y = pk2(wp[(c0 + 2) * 32] * scv, wp[(c0 + 3) * 32] * scv);
        r.z = pk2(wp[(c0 + 4) * 32] * scv, wp[(c0 + 5) * 32] * scv);
        r.w = pk2(wp[(c0 + 6) * 32] * scv, wp[(c0 + 7) * 32] * scv);
        Bfg[t] = r;
    }
    if (g0 < 12) {      // zero row n of xbf/tmpbf/hb (gather target for missing nbrs)
        uint4 z = make_uint4(0, 0, 0, 0);
        if (g0 < 4)       ((uint4*)(xbf + (size_t)n * 32))[g0] = z;
        else if (g0 < 8)  ((uint4*)(tmpbf + (size_t)n * 32))[g0 - 4] = z;
        else              ((uint4*)(hb + (size_t)n * 32))[g0 - 8] = z;
    }
    gsync(cnt, 2);

    // ---- conv layers ----
    int l = tid & 63;
    int q = l & 31, h5 = l >> 5;
    int gw = (int)blockIdx.x * 4 + (tid >> 6);
    int totalW = (int)gridDim.x * 4;
    int ntile = (n + 31) >> 5;

    for (int t = gw; t < ntile; t += totalW)
        conv_tile<false, false>(t, xbf, nullptr, tmpbf, Bfg + 0 * BSZ, sh_all + 0,   roff, n, l, q, h5);
    gsync(cnt, 3);
    for (int t = gw; t < ntile; t += totalW)
        conv_tile<true,  false>(t, tmpbf, xbf, hb,      Bfg + 1 * BSZ, sh_all + 32,  roff, n, l, q, h5);
    gsync(cnt, 4);
    for (int t = gw; t < ntile; t += totalW)
        conv_tile<false, false>(t, hb, nullptr, tmpbf,  Bfg + 2 * BSZ, sh_all + 64,  roff, n, l, q, h5);
    gsync(cnt, 5);
    for (int t = gw; t < ntile; t += totalW)
        conv_tile<true,  false>(t, tmpbf, hb, xbf,      Bfg + 3 * BSZ, sh_all + 96,  roff, n, l, q, h5);
    gsync(cnt, 6);
    for (int t = gw; t < ntile; t += totalW)
        conv_tile<false, false>(t, xbf, nullptr, tmpbf, Bfg + 4 * BSZ, sh_all + 128, roff, n, l, q, h5);
    gsync(cnt, 7);
    for (int t = gw; t < ntile; t += totalW)
        conv_tile<true,  true >(t, tmpbf, xbf, out,     Bfg + 5 * BSZ, sh_all + 160, roff, n, l, q, h5);
}

extern "C" void kernel_launch(void* const* d_in, const int* in_sizes, int n_in,
                              void* d_out, int out_size, void* d_ws, size_t ws_size,
                              hipStream_t stream)
{
    const float* feats = (const float*)d_in[0];
    const float* Wk    = (const float*)d_in[1];  // [3][2][9][32][32]
    const float* bias  = (const float*)d_in[2];
    const float* gamma = (const float*)d_in[3];
    const float* beta  = (const float*)d_in[4];
    const float* mean  = (const float*)d_in[5];
    const float* var   = (const float*)d_in[6];
    const int* cb = (const int*)d_in[7];
    const int* cy = (const int*)d_in[8];
    const int* cx = (const int*)d_in[9];
    float* out = (float*)d_out;
    int n = in_sizes[0] / NC;

    char* ws = (char*)d_ws;
    int*            idx_map = (int*)(ws + 0);                   // 33,177,600 B
    unsigned*       pkey    = (unsigned*)(ws + 33177600);       //    800,000 B
    int*            roff    = (int*)(ws + 33977600);            //  7,200,000 B
    uint4*          Bfg     = (uint4*)(ws + 41177600);          //    110,592 B
    float*          sh_all  = (float*)(ws + 41288192);          //        768 B
    int*            cnt     = (int*)(ws + 41288960);            //         64 B
    unsigned short* xbf     = (unsigned short*)(ws + 41289024); // 12,800,064 B
    unsigned short* tmpbf   = (unsigned short*)(ws + 54089152); // 12,800,064 B
    unsigned short* hb      = (unsigned short*)(ws + 66889280); // 12,800,064 B

    (void)hipMemsetAsync(cnt, 0, 64, stream);

    int maxB = 0;
    (void)hipOccupancyMaxActiveBlocksPerMultiprocessor(&maxB, k_all, 256, 0);
    if (maxB < 1) maxB = 1;
    int G = maxB * 256;                      // MI355X: 256 CUs (co-residency bound)
    int Gneed = ((n + 31) / 32 + 3) / 4;     // one tile per wave
    if (G > Gneed) G = Gneed;

    void* args[] = { (void*)&cb, (void*)&cy, (void*)&cx, (void*)&feats, (void*)&Wk,
                     (void*)&bias, (void*)&gamma, (void*)&beta, (void*)&mean,
                     (void*)&var, (void*)&idx_map, (void*)&pkey, (void*)&roff,
                     (void*)&Bfg, (void*)&sh_all, (void*)&xbf, (void*)&tmpbf,
                     (void*)&hb, (void*)&out, (void*)&cnt, (void*)&n };
    (void)hipLaunchCooperativeKernel((const void*)k_all, dim3(G), dim3(256),
                                     args, 0, stream);
}

// Round 19
// 153.119 us; speedup vs baseline: 10.9756x; 10.9756x over previous
//
#include <hip/hip_runtime.h>

#define CB 4
#define CH 1440
#define CW 1440
#define NC 32
#define EPSV 1e-3f
#define NBKT (CB * CH)          // 5760 (b,y) buckets
#define BSZ (9 * 2 * 64)        // uint4s per layer of Bfg

typedef __attribute__((ext_vector_type(8))) short bf16x8;
typedef __attribute__((ext_vector_type(16))) float f32x16;

union U16 { uint4 u; bf16x8 v; };

__device__ __forceinline__ unsigned pk2(float a, float b) {
    unsigned ua = __float_as_uint(a), ub = __float_as_uint(b);
    ua += 0x7fffu + ((ua >> 16) & 1u);
    ub += 0x7fffu + ((ub >> 16) & 1u);
    return (ua >> 16) | (ub & 0xffff0000u);
}
__device__ __forceinline__ float bfl(unsigned u) { return __uint_as_float(u << 16); }
__device__ __forceinline__ float bfh(unsigned u) { return __uint_as_float(u & 0xffff0000u); }

// ---------------- kernel 1: key + center-cell clear + (b,y)-bucket histogram -------
__global__ __launch_bounds__(256) void k_hist(
    const int* __restrict__ cb, const int* __restrict__ cy, const int* __restrict__ cx,
    int* __restrict__ idx_map, unsigned* __restrict__ pkey, int* __restrict__ hist,
    int n)
{
    int i = blockIdx.x * blockDim.x + threadIdx.x;
    if (i >= n) return;
    unsigned key = ((unsigned)cb[i] * CH + (unsigned)cy[i]) * CW + (unsigned)cx[i];
    pkey[i] = key;
    idx_map[key] = -1;                       // center-only clear (r13 scheme)
    atomicAdd(&hist[key / CW], 1);           // bucket = b*CH+y
}

// ---------------- kernel 2: one-block exclusive scan + bcnt zero + zero rows -------
__global__ __launch_bounds__(1024) void k_scan(
    const int* __restrict__ hist, int* __restrict__ bstart, int* __restrict__ bcnt,
    unsigned short* __restrict__ z0, unsigned short* __restrict__ z1,
    unsigned short* __restrict__ z2, int n)
{
    __shared__ int ps[1024];
    int tid = threadIdx.x;
    const int PB = 6;                        // 1024*6 = 6144 >= 5760
    int base = tid * PB;
    int loc[PB]; int s = 0;
    #pragma unroll
    for (int j = 0; j < PB; ++j) {
        int idx = base + j;
        int v = (idx < NBKT) ? hist[idx] : 0;
        loc[j] = s; s += v;
    }
    ps[tid] = s;
    __syncthreads();
    for (int off = 1; off < 1024; off <<= 1) {
        int u = (tid >= off) ? ps[tid - off] : 0;
        __syncthreads();
        ps[tid] += u;
        __syncthreads();
    }
    int excl = (tid > 0) ? ps[tid - 1] : 0;
    #pragma unroll
    for (int j = 0; j < PB; ++j)
        if (base + j < NBKT) bstart[base + j] = excl + loc[j];
    for (int i = tid; i < NBKT; i += 1024) bcnt[i] = 0;
    if (tid < 12) {                          // zero row n of the 3 bf16 buffers
        uint4 z = make_uint4(0, 0, 0, 0);
        if (tid < 4)       ((uint4*)(z0 + (size_t)n * 32))[tid] = z;
        else if (tid < 8)  ((uint4*)(z1 + (size_t)n * 32))[tid - 4] = z;
        else               ((uint4*)(z2 + (size_t)n * 32))[tid - 8] = z;
    }
}

// ---------------- kernel 3: rank assignment + map build (orig-index winners) -------
__global__ __launch_bounds__(256) void k_rank(
    const unsigned* __restrict__ pkey, const int* __restrict__ bstart,
    int* __restrict__ bcnt, int* __restrict__ rankof, int* __restrict__ sortidx,
    unsigned* __restrict__ skey, int* __restrict__ idx_map, int n)
{
    int i = blockIdx.x * blockDim.x + threadIdx.x;
    if (i >= n) return;
    unsigned key = pkey[i];
    int bu = key / CW;
    int r = bstart[bu] + atomicAdd(&bcnt[bu], 1);
    rankof[i] = r;
    sortidx[r] = i;
    skey[r] = key;
    atomicMax(&idx_map[key], i);             // numpy last-write-wins by ORIGINAL idx
}

__device__ __forceinline__ int vquery(const int* __restrict__ idx_map,
                                      const unsigned* __restrict__ pkey,
                                      unsigned cell, int n)
{
    int v = idx_map[cell];
    if (v < 0 || v >= n) return -1;
    return (pkey[v] == cell) ? v : -1;
}

// ---------------- kernel 4 (fused): rank-space rulebook + sorted cvt + wcvt --------
__global__ __launch_bounds__(256) void k_prep(
    const unsigned* __restrict__ pkey, const unsigned* __restrict__ skey,
    const int* __restrict__ idx_map, const int* __restrict__ rankof,
    const int* __restrict__ sortidx, int* __restrict__ roff,
    const float* __restrict__ feats, unsigned short* __restrict__ xbf,
    const float* __restrict__ Wk, uint4* __restrict__ Bfg,
    const float* __restrict__ bias, const float* __restrict__ gamma,
    const float* __restrict__ beta, const float* __restrict__ mean,
    const float* __restrict__ var, float* __restrict__ sh_all, int n)
{
    int RB = (n + 255) >> 8;
    int CVT = (n * 2 + 255) >> 8;
    int bx = blockIdx.x;

    if (bx < RB) {                 // ---- rulebook in RANK space ----
        int r = bx * 256 + threadIdx.x;
        if (r >= n) return;
        unsigned key = skey[r];
        unsigned x = key % CW;
        unsigned y = (key / CW) % CH;
        roff[4 * n + r] = rankof[idx_map[key]] * 64;   // own cell: trusted
        #pragma unroll
        for (int k = 0; k < 9; ++k) {
            if (k == 4) continue;
            int dy = k / 3 - 1, dx = k % 3 - 1;
            int ny = (int)y + dy, nx = (int)x + dx;
            int nb = -1;
            if (ny >= 0 && ny < CH && nx >= 0 && nx < CW)
                nb = vquery(idx_map, pkey, key + dy * CW + dx, n);
            roff[k * n + r] = (nb >= 0) ? rankof[nb] * 64 : -1;
        }
    } else if (bx < RB + CVT) {    // ---- feats -> bf16, gathered into SORTED order --
        int t = (bx - RB) * 256 + threadIdx.x;   // t over n*2 half-rows
        if (t < n * 2) {
            int r = t >> 1, half = t & 1;
            const float* src = feats + (size_t)sortidx[r] * 32 + half * 16;
            float4 a0 = *(const float4*)(src);
            float4 a1 = *(const float4*)(src + 4);
            float4 a2 = *(const float4*)(src + 8);
            float4 a3 = *(const float4*)(src + 12);
            uint4 r0, r1;
            r0.x = pk2(a0.x, a0.y); r0.y = pk2(a0.z, a0.w);
            r0.z = pk2(a1.x, a1.y); r0.w = pk2(a1.z, a1.w);
            r1.x = pk2(a2.x, a2.y); r1.y = pk2(a2.z, a2.w);
            r1.z = pk2(a3.x, a3.y); r1.w = pk2(a3.z, a3.w);
            *(uint4*)(xbf + (size_t)r * 32 + half * 16) = r0;
            *(uint4*)(xbf + (size_t)r * 32 + half * 16 + 8) = r1;
        }
    } else {                       // ---- W*sc -> bf16 B-frags + sh ----
        int t = (bx - RB - CVT) * 256 + threadIdx.x;
        if (t >= 6 * 9 * 2 * 64) return;
        int l = t & 63, h = (t >> 6) & 1;
        int rest = t >> 7;
        int k = rest % 9, layer = rest / 9;
        int o = l & 31;
        int lo = layer * 32 + o;
        float scv = gamma[lo] * rsqrtf(var[lo] + EPSV);
        if (k == 0 && h == 0 && l < 32)
            sh_all[lo] = (bias[lo] - mean[lo]) * scv + beta[lo];
        int c0 = h * 16 + 8 * (l >> 5);
        const float* wp = Wk + (size_t)layer * 9216 + k * 1024 + o;   // [c][o]
        uint4 r;
        r.x = pk2(wp[(c0 + 0) * 32] * scv, wp[(c0 + 1) * 32] * scv);
        r.y = pk2(wp[(c0 + 2) * 32] * scv, wp[(c0 + 3) * 32] * scv);
        r.z = pk2(wp[(c0 + 4) * 32] * scv, wp[(c0 + 5) * 32] * scv);
        r.w = pk2(wp[(c0 + 6) * 32] * scv, wp[(c0 + 7) * 32] * scv);
        Bfg[t] = r;
    }
}

// ---------------- kernel 5: gather-K 32x32x16 MFMA conv (rank space) ---------------
// r14 body unchanged; F32OUT layer scatter-writes full 128B rows to original order.
template<bool ADD_ID, bool F32OUT>
__global__ __launch_bounds__(256, 6) void k_conv(
    const unsigned short* __restrict__ in,   // bf16 [n+1][32] (rank space)
    const unsigned short* __restrict__ idn,  // bf16 [n][32]   (rank space)
    void* __restrict__ outv,                 // bf16 (rank) or f32 (orig)
    const uint4* __restrict__ Bf,
    const float* __restrict__ sh,
    const int* __restrict__ roff, const int* __restrict__ sortidx, int n)
{
    int l = threadIdx.x & 63, wv = threadIdx.x >> 6;
    int q = l & 31, h5 = l >> 5;

    int ntile = (n + 31) >> 5;
    int tile = blockIdx.x * 4 + wv;
    if (tile >= ntile) return;

    const int zoff = n * 64;
    const char* inB = (const char*)in;

    int p0 = tile << 5;
    int pr = p0 + q;
    bool rowok = pr < n;
    int prc = rowok ? pr : n - 1;

    int rk[9];
    #pragma unroll
    for (int k = 0; k < 9; ++k) rk[k] = roff[(size_t)k * n + prc];

    f32x16 acc = {0.f,0.f,0.f,0.f,0.f,0.f,0.f,0.f,0.f,0.f,0.f,0.f,0.f,0.f,0.f,0.f};

    #pragma unroll
    for (int g = 0; g < 3; ++g) {
        bool act[3];
        U16 a0[3], a1[3];
        #pragma unroll
        for (int j = 0; j < 3; ++j) {
            int k = g * 3 + j;
            act[j] = __any(rk[k] >= 0);
            if (act[j]) {
                int off = (rowok && rk[k] >= 0) ? rk[k] : zoff;
                const char* ap = inB + off + h5 * 16;
                a0[j].u = *(const uint4*)(ap);
                a1[j].u = *(const uint4*)(ap + 32);
            }
        }
        #pragma unroll
        for (int j = 0; j < 3; ++j) {
            int k = g * 3 + j;
            if (act[j]) {
                U16 b0, b1;
                b0.u = Bf[(k * 2 + 0) * 64 + l];
                b1.u = Bf[(k * 2 + 1) * 64 + l];
                acc = __builtin_amdgcn_mfma_f32_32x32x16_bf16(b0.v, a0[j].v, acc, 0, 0, 0);
                acc = __builtin_amdgcn_mfma_f32_32x32x16_bf16(b1.v, a1[j].v, acc, 0, 0, 0);
            }
        }
    }

    if (rowok) {
        int orow = F32OUT ? sortidx[pr] : pr;
        #pragma unroll
        for (int g = 0; g < 4; ++g) {
            int ch = g * 8 + 4 * h5;
            float4 s4 = *(const float4*)(sh + ch);
            float y0 = acc[g * 4 + 0] + s4.x;
            float y1 = acc[g * 4 + 1] + s4.y;
            float y2 = acc[g * 4 + 2] + s4.z;
            float y3 = acc[g * 4 + 3] + s4.w;
            if (ADD_ID) {
                uint2 iv = *(const uint2*)(idn + (size_t)pr * 32 + ch);
                y0 += bfl(iv.x); y1 += bfh(iv.x);
                y2 += bfl(iv.y); y3 += bfh(iv.y);
            }
            y0 = fmaxf(y0, 0.f); y1 = fmaxf(y1, 0.f);
            y2 = fmaxf(y2, 0.f); y3 = fmaxf(y3, 0.f);
            if (F32OUT) {
                *(float4*)((float*)outv + (size_t)orow * 32 + ch) =
                    make_float4(y0, y1, y2, y3);
            } else {
                uint2 r;
                r.x = pk2(y0, y1); r.y = pk2(y2, y3);
                *(uint2*)((unsigned short*)outv + (size_t)pr * 32 + ch) = r;
            }
        }
    }
}

extern "C" void kernel_launch(void* const* d_in, const int* in_sizes, int n_in,
                              void* d_out, int out_size, void* d_ws, size_t ws_size,
                              hipStream_t stream)
{
    const float* feats = (const float*)d_in[0];
    const float* Wk    = (const float*)d_in[1];  // [3][2][9][32][32]
    const float* bias  = (const float*)d_in[2];
    const float* gamma = (const float*)d_in[3];
    const float* beta  = (const float*)d_in[4];
    const float* mean  = (const float*)d_in[5];
    const float* var   = (const float*)d_in[6];
    const int* cb = (const int*)d_in[7];
    const int* cy = (const int*)d_in[8];
    const int* cx = (const int*)d_in[9];
    float* out = (float*)d_out;
    int n = in_sizes[0] / NC;

    char* ws = (char*)d_ws;
    int*            idx_map = (int*)(ws + 0);                   // 33,177,600 B
    unsigned*       pkey    = (unsigned*)(ws + 33177600);       //    800,000 B
    int*            roff    = (int*)(ws + 33977600);            //  7,200,000 B
    uint4*          Bfg     = (uint4*)(ws + 41177600);          //    110,592 B
    float*          sh_all  = (float*)(ws + 41288192);          //        768 B
    int*            hist    = (int*)(ws + 41288960);            //     23,040 B
    int*            bcnt    = (int*)(ws + 41312000);            //     23,040 B
    int*            bstart  = (int*)(ws + 41335040);            //     23,040 B
    int*            rankof  = (int*)(ws + 41358080);            //    800,000 B
    int*            sortidx = (int*)(ws + 42158080);            //    800,000 B
    unsigned*       skey    = (unsigned*)(ws + 42958080);       //    800,000 B
    unsigned short* xbf     = (unsigned short*)(ws + 43758080); // 12,800,064 B
    unsigned short* tmpbf   = (unsigned short*)(ws + 56558144); // 12,800,064 B
    unsigned short* hb      = (unsigned short*)(ws + 69358208); // 12,800,064 B

    (void)hipMemsetAsync(hist, 0, 23040 * 2, stream);   // hist + bcnt... bcnt re-zeroed in k_scan anyway

    int RB  = (n + 255) / 256;
    int CVT = (n * 2 + 255) / 256;
    k_hist<<<RB, 256, 0, stream>>>(cb, cy, cx, idx_map, pkey, hist, n);
    k_scan<<<1, 1024, 0, stream>>>(hist, bstart, bcnt,
        xbf, tmpbf, hb, n);
    k_rank<<<RB, 256, 0, stream>>>(pkey, bstart, bcnt, rankof, sortidx, skey,
        idx_map, n);
    k_prep<<<RB + CVT + 27, 256, 0, stream>>>(
        pkey, skey, idx_map, rankof, sortidx, roff, feats, xbf, Wk, Bfg,
        bias, gamma, beta, mean, var, sh_all, n);

    const int ntile = (n + 31) / 32;
    const int G = (ntile + 3) / 4;   // one tile per wave, single pass

    k_conv<false, false><<<G, 256, 0, stream>>>(xbf, nullptr, tmpbf,
        Bfg + 0 * BSZ, sh_all + 0,   roff, sortidx, n);
    k_conv<true,  false><<<G, 256, 0, stream>>>(tmpbf, xbf, hb,
        Bfg + 1 * BSZ, sh_all + 32,  roff, sortidx, n);
    k_conv<false, false><<<G, 256, 0, stream>>>(hb, nullptr, tmpbf,
        Bfg + 2 * BSZ, sh_all + 64,  roff, sortidx, n);
    k_conv<true,  false><<<G, 256, 0, stream>>>(tmpbf, hb, xbf,
        Bfg + 3 * BSZ, sh_all + 96,  roff, sortidx, n);
    k_conv<false, false><<<G, 256, 0, stream>>>(xbf, nullptr, tmpbf,
        Bfg + 4 * BSZ, sh_all + 128, roff, sortidx, n);
    k_conv<true,  true ><<<G, 256, 0, stream>>>(tmpbf, xbf, out,
        Bfg + 5 * BSZ, sh_all + 160, roff, sortidx, n);
}

// Round 20
// 128.965 us; speedup vs baseline: 13.0313x; 1.1873x over previous
//
#include <hip/hip_runtime.h>

#define NB_ 3
#define CB 4
#define CH 1440
#define CW 1440
#define NC 32
#define EPSV 1e-3f

typedef __attribute__((ext_vector_type(8))) short bf16x8;
typedef __attribute__((ext_vector_type(16))) float f32x16;

union U16 { uint4 u; bf16x8 v; };

__device__ __forceinline__ unsigned pk2(float a, float b) {
    unsigned ua = __float_as_uint(a), ub = __float_as_uint(b);
    ua += 0x7fffu + ((ua >> 16) & 1u);
    ub += 0x7fffu + ((ub >> 16) & 1u);
    return (ua >> 16) | (ub & 0xffff0000u);
}
__device__ __forceinline__ unsigned short f2b(float a) {
    unsigned u = __float_as_uint(a);
    u += 0x7fffu + ((u >> 16) & 1u);
    return (unsigned short)(u >> 16);
}
__device__ __forceinline__ float b2f(unsigned short s) {
    return __uint_as_float(((unsigned)s) << 16);
}

// ---------------- kernel 0: clear ONLY center cells + emit packed keys -------------
// Neighbor cells are never cleared; rulebook verifies instead. Any multi-point cell
// is some point's own cell (always cleared+rebuilt); a non-point cell can never pass
// verification (no point has its key) -> garbage-safe incl. unpoisoned first call.
// Stale winners from prior replays == current winners (point set constant) and
// atomicMax is idempotent -> deterministic across replays.
__global__ __launch_bounds__(256) void k_clear(
    const int* __restrict__ cb, const int* __restrict__ cy, const int* __restrict__ cx,
    int* __restrict__ idx_map, unsigned* __restrict__ pkey, int n)
{
    int i = blockIdx.x * blockDim.x + threadIdx.x;
    if (i >= n) return;
    unsigned key = ((unsigned)cb[i] * CH + (unsigned)cy[i]) * CW + (unsigned)cx[i];
    pkey[i] = key;
    idx_map[key] = -1;
}

// ---------------- kernel 1: build idx_map via atomicMax (numpy last-write-wins) ----
__global__ __launch_bounds__(256) void k_build_map(
    const unsigned* __restrict__ pkey, int* __restrict__ idx_map, int n)
{
    int i = blockIdx.x * blockDim.x + threadIdx.x;
    if (i < n) atomicMax(&idx_map[pkey[i]], i);
}

__device__ __forceinline__ int vquery(const int* __restrict__ idx_map,
                                      const unsigned* __restrict__ pkey,
                                      unsigned cell, int n)
{
    int v = idx_map[cell];
    if (v < 0 || v >= n) return -1;
    return (pkey[v] == cell) ? v : -1;
}

// ---------------- kernel 2 (fused): rulebook + feats->bf16 + W->B-frags ------------
// Block-range split: [0,RB) rulebook, [RB,RB+CVT) cvt, [RB+CVT,RB+CVT+27) wcvt.
__global__ __launch_bounds__(256) void k_prep(
    const unsigned* __restrict__ pkey, const int* __restrict__ idx_map,
    int* __restrict__ roff,
    const float* __restrict__ feats, unsigned short* __restrict__ xbf,
    const float* __restrict__ Wk, uint4* __restrict__ Bfg,
    unsigned short* __restrict__ z0, unsigned short* __restrict__ z1,
    unsigned short* __restrict__ z2, int n)
{
    int RB = (n + 255) >> 8;
    int CVT = ((n * NC / 8) + 255) >> 8;
    int bx = blockIdx.x;

    if (bx < RB) {                       // ---- rulebook: roff[9][n] byte offsets ----
        int i = bx * 256 + threadIdx.x;
        if (i >= n) return;
        unsigned key = pkey[i];
        unsigned x = key % CW;
        unsigned y = (key / CW) % CH;
        roff[4 * n + i] = idx_map[key] * 64;   // own cell: cleared+built, trusted
        #pragma unroll
        for (int k = 0; k < 9; ++k) {
            if (k == 4) continue;
            int dy = k / 3 - 1, dx = k % 3 - 1;
            int ny = (int)y + dy, nx = (int)x + dx;
            int nb = -1;
            if (ny >= 0 && ny < CH && nx >= 0 && nx < CW)
                nb = vquery(idx_map, pkey, key + dy * CW + dx, n);
            roff[k * n + i] = (nb >= 0) ? nb * 64 : -1;
        }
    } else if (bx < RB + CVT) {          // ---- feats f32 -> bf16 --------------------
        int i = ((bx - RB) * 256 + threadIdx.x) * 8;
        if (i + 8 <= n * NC) {
            float4 a0 = *(const float4*)(feats + i);
            float4 a1 = *(const float4*)(feats + i + 4);
            uint4 r;
            r.x = pk2(a0.x, a0.y); r.y = pk2(a0.z, a0.w);
            r.z = pk2(a1.x, a1.y); r.w = pk2(a1.z, a1.w);
            *(uint4*)(xbf + i) = r;
        }
    } else {                             // ---- W -> bf16 B-frags + zero rows --------
        int wb = bx - RB - CVT;
        if (wb == 0 && threadIdx.x < 12) {
            uint4 z = make_uint4(0, 0, 0, 0);
            int tt = threadIdx.x;
            if (tt < 4)       ((uint4*)z0)[tt] = z;
            else if (tt < 8)  ((uint4*)z1)[tt - 4] = z;
            else              ((uint4*)z2)[tt - 8] = z;
        }
        int t = wb * 256 + threadIdx.x;
        if (t >= 6 * 9 * 2 * 64) return;
        int l = t & 63, h = (t >> 6) & 1;
        int rest = t >> 7;
        int k = rest % 9, layer = rest / 9;
        int o = l & 31;
        int c0 = h * 16 + 8 * (l >> 5);
        const float* wp = Wk + (size_t)layer * 9216 + k * 1024 + o;   // [c][o]
        uint4 r;
        r.x = pk2(wp[(c0 + 0) * 32], wp[(c0 + 1) * 32]);
        r.y = pk2(wp[(c0 + 2) * 32], wp[(c0 + 3) * 32]);
        r.z = pk2(wp[(c0 + 4) * 32], wp[(c0 + 5) * 32]);
        r.w = pk2(wp[(c0 + 6) * 32], wp[(c0 + 7) * 32]);
        Bfg[t] = r;
    }
}

// ---------------- kernel 4: gather-K 32x32x16 MFMA conv + BN (+identity) + ReLU ----
// (r11 body: one wave = one 32-pt tile, single pass, bound (256,6) -> 24 waves/CU.
//  Best-measured configuration of the session: 128.4us total.)
template<bool ADD_ID, bool F32OUT>
__global__ __launch_bounds__(256, 6) void k_conv(
    const unsigned short* __restrict__ in,   // bf16 [n+1][32], row n = zeros
    const unsigned short* __restrict__ idn,  // bf16 [n][32]
    void* __restrict__ outv,                 // bf16 or f32 [n][32]
    const uint4* __restrict__ Bf,            // [9][2][64] B-frags (this layer)
    const float* __restrict__ bias,
    const float* __restrict__ gamma, const float* __restrict__ beta,
    const float* __restrict__ mean, const float* __restrict__ var,
    const int* __restrict__ roff, int n)
{
    int l = threadIdx.x & 63, wv = threadIdx.x >> 6;
    int q = l & 31, h5 = l >> 5;

    int ntile = (n + 31) >> 5;
    int tile = blockIdx.x * 4 + wv;
    if (tile >= ntile) return;

    float sc = gamma[q] * rsqrtf(var[q] + EPSV);
    float sh = (bias[q] - mean[q]) * sc + beta[q];

    const int zoff = n * 64;
    const char* inB = (const char*)in;

    int p0 = tile << 5;
    int pr = p0 + q;
    bool rowok = pr < n;
    int prc = rowok ? pr : n - 1;

    int rk[9];
    #pragma unroll
    for (int k = 0; k < 9; ++k) rk[k] = roff[(size_t)k * n + prc];

    f32x16 acc = {0.f,0.f,0.f,0.f,0.f,0.f,0.f,0.f,0.f,0.f,0.f,0.f,0.f,0.f,0.f,0.f};

    #pragma unroll
    for (int g = 0; g < 3; ++g) {
        bool act[3];
        U16 a0[3], a1[3];
        #pragma unroll
        for (int j = 0; j < 3; ++j) {
            int k = g * 3 + j;
            act[j] = __any(rk[k] >= 0);
            if (act[j]) {
                int off = (rowok && rk[k] >= 0) ? rk[k] : zoff;
                const char* ap = inB + off + h5 * 16;
                a0[j].u = *(const uint4*)(ap);        // chans h5*8    ..+8 (K-half 0)
                a1[j].u = *(const uint4*)(ap + 32);   // chans 16+h5*8 ..+8 (K-half 1)
            }
        }
        #pragma unroll
        for (int j = 0; j < 3; ++j) {
            int k = g * 3 + j;
            if (act[j]) {
                U16 b0, b1;
                b0.u = Bf[(k * 2 + 0) * 64 + l];
                b1.u = Bf[(k * 2 + 1) * 64 + l];
                acc = __builtin_amdgcn_mfma_f32_32x32x16_bf16(a0[j].v, b0.v, acc, 0, 0, 0);
                acc = __builtin_amdgcn_mfma_f32_32x32x16_bf16(a1[j].v, b1.v, acc, 0, 0, 0);
            }
        }
    }

    #pragma unroll
    for (int r = 0; r < 16; ++r) {
        int p = p0 + (r & 3) + 8 * (r >> 2) + 4 * h5;
        if (p < n) {
            float y = acc[r] * sc + sh;
            if (ADD_ID) y += b2f(idn[(size_t)p * 32 + q]);
            y = fmaxf(y, 0.f);
            if (F32OUT) ((float*)outv)[(size_t)p * 32 + q] = y;
            else ((unsigned short*)outv)[(size_t)p * 32 + q] = f2b(y);
        }
    }
}

extern "C" void kernel_launch(void* const* d_in, const int* in_sizes, int n_in,
                              void* d_out, int out_size, void* d_ws, size_t ws_size,
                              hipStream_t stream)
{
    const float* feats = (const float*)d_in[0];
    const float* Wk    = (const float*)d_in[1];  // [3][2][9][32][32]
    const float* bias  = (const float*)d_in[2];
    const float* gamma = (const float*)d_in[3];
    const float* beta  = (const float*)d_in[4];
    const float* mean  = (const float*)d_in[5];
    const float* var   = (const float*)d_in[6];
    const int* cb = (const int*)d_in[7];
    const int* cy = (const int*)d_in[8];
    const int* cx = (const int*)d_in[9];
    float* out = (float*)d_out;
    int n = in_sizes[0] / NC;

    char* ws = (char*)d_ws;
    int*            idx_map = (int*)(ws + 0);                   // 33,177,600 B
    unsigned*       pkey    = (unsigned*)(ws + 33177600);       //    800,000 B
    int*            roff    = (int*)(ws + 33977600);            //  7,200,000 B
    uint4*          Bfg     = (uint4*)(ws + 41177600);          //    110,592 B
    unsigned short* xbf     = (unsigned short*)(ws + 41288192); // 12,800,064 B
    unsigned short* tmpbf   = (unsigned short*)(ws + 54088256); // 12,800,064 B
    unsigned short* hb      = (unsigned short*)(ws + 66888320); // 12,800,064 B

    int RB  = (n + 255) / 256;
    int CVT = ((n * NC / 8) + 255) / 256;
    k_clear<<<RB, 256, 0, stream>>>(cb, cy, cx, idx_map, pkey, n);
    k_build_map<<<RB, 256, 0, stream>>>(pkey, idx_map, n);
    k_prep<<<RB + CVT + 27, 256, 0, stream>>>(
        pkey, idx_map, roff, feats, xbf, Wk, Bfg,
        xbf + (size_t)n * 32, tmpbf + (size_t)n * 32, hb + (size_t)n * 32, n);

    const int ntile = (n + 31) / 32;
    const int G = (ntile + 3) / 4;   // one tile per wave, single pass
    const int BSZ = 9 * 2 * 64;      // uint4s per layer of Bfg

    k_conv<false, false><<<G, 256, 0, stream>>>(xbf, nullptr, tmpbf,
        Bfg + 0 * BSZ, bias + 0,  gamma + 0,  beta + 0,  mean + 0,  var + 0,  roff, n);
    k_conv<true,  false><<<G, 256, 0, stream>>>(tmpbf, xbf, hb,
        Bfg + 1 * BSZ, bias + 32, gamma + 32, beta + 32, mean + 32, var + 32, roff, n);
    k_conv<false, false><<<G, 256, 0, stream>>>(hb, nullptr, tmpbf,
        Bfg + 2 * BSZ, bias + 64, gamma + 64, beta + 64, mean + 64, var + 64, roff, n);
    k_conv<true,  false><<<G, 256, 0, stream>>>(tmpbf, hb, xbf,
        Bfg + 3 * BSZ, bias + 96, gamma + 96, beta + 96, mean + 96, var + 96, roff, n);
    k_conv<false, false><<<G, 256, 0, stream>>>(xbf, nullptr, tmpbf,
        Bfg + 4 * BSZ, bias + 128, gamma + 128, beta + 128, mean + 128, var + 128, roff, n);
    k_conv<true,  true><<<G, 256, 0, stream>>>(tmpbf, xbf, out,
        Bfg + 5 * BSZ, bias + 160, gamma + 160, beta + 160, mean + 160, var + 160, roff, n);
}